// Round 11
// baseline (356.924 us; speedup 1.0000x reference)
//
#include <hip/hip_runtime.h>

// B=2, T=2048, C=2048, H=16, HD=128, P=256
// s=mean|W| -> WT ternary bf16 [n][k] -> async-LDS bf16 GEMMs -> flash -> out GEMM
// R1:  GEMM folded single-barrier dbuf BK=64, 128x128, 256 thr == FROZEN (2-phase ceiling)
// R8:  RoPE fused into Q/K GEMM epilogue; build_all + gemm_qkv(z=3)          (363.7us)
// R9:  out-GEMM chunked T1 XCD swizzle (kept)                                (354.4us)
// R10: gemm_qkv z-slab identity + per-slab chunked swizzle -> 733 TF ceiling (355.1us)
// R11: pre_kernel = reduce1 || cast (one launch); reduce2 eliminated -- every consumer
//      derives s from partials (64-load wave-0 preamble). Fused path: 5 launches.

typedef __attribute__((ext_vector_type(8))) short short8;
typedef __attribute__((ext_vector_type(4))) float f32x4;
typedef unsigned short u16;
typedef unsigned int u32;

__device__ __forceinline__ float bf2f(u16 u) {
    u32 x = ((u32)u) << 16;
    return __builtin_bit_cast(float, x);
}
__device__ __forceinline__ u16 f2bf(float f) {
    u32 x = __builtin_bit_cast(u32, f);
    x += 0x7fffu + ((x >> 16) & 1u);   // RNE
    return (u16)(x >> 16);
}
__device__ __forceinline__ u16 f2bf_trunc(float f) {
    return (u16)(__builtin_bit_cast(u32, f) >> 16);
}
__device__ __forceinline__ u32 pack2(u16 a, u16 b) { return (u32)a | ((u32)b << 16); }

__device__ __forceinline__ void async16(const void* g, void* l) {
    __builtin_amdgcn_global_load_lds((const __attribute__((address_space(1))) u32*)g,
                                     (__attribute__((address_space(3))) u32*)l, 16, 0, 0);
}

// derive s = mean|W| + eps from the 64 per-weight partials (wave 0 only; all threads return it)
__device__ __forceinline__ float derive_s(const float* __restrict__ partials, int wsel,
                                          int tid, float* sh) {
    if (tid < 64) {
        float v = partials[wsel * 64 + tid];
#pragma unroll
        for (int off = 1; off < 64; off <<= 1) v += __shfl_xor(v, off, 64);
        if (tid == 0) *sh = v / 524288.0f + 1e-8f;
    }
    __syncthreads();
    return *sh;
}

__device__ const int d_OCT_IDX[8][8] = {
    {0,1,2,3,4,5,6,7},{1,0,3,2,5,4,7,6},{2,3,0,1,6,7,4,5},{3,2,1,0,7,6,5,4},
    {4,5,6,7,0,1,2,3},{5,4,7,6,1,0,3,2},{6,7,4,5,2,3,0,1},{7,6,5,4,3,2,1,0}};
__device__ const float d_OCT_SIGN[8][8] = {
    { 1, 1, 1, 1, 1, 1, 1, 1},{ 1,-1, 1,-1, 1,-1,-1, 1},{ 1,-1,-1, 1, 1, 1,-1,-1},
    { 1, 1,-1,-1, 1,-1, 1,-1},{ 1,-1,-1,-1,-1, 1, 1, 1},{ 1, 1,-1, 1,-1,-1,-1, 1},
    { 1, 1, 1,-1,-1, 1,-1,-1},{ 1,-1, 1, 1,-1,-1, 1,-1}};

// ---- pre: blocks [0,256) = |W| partial sums; blocks [256,4352) = x f32->bf16 cast ----
__global__ __launch_bounds__(256) void pre_kernel(
    const float* __restrict__ w0, const float* __restrict__ w1,
    const float* __restrict__ w2, const float* __restrict__ w3,
    const float* __restrict__ X, float* __restrict__ partials, u16* __restrict__ Xb) {
    __shared__ float r4[4];
    int bid = blockIdx.x, tid = threadIdx.x;
    if (bid < 256) {
        int wsel = bid >> 6, part = bid & 63;
        const float* W = wsel == 0 ? w0 : wsel == 1 ? w1 : wsel == 2 ? w2 : w3;
        int base = part * 8192 + tid;
        float acc = 0.f;
#pragma unroll
        for (int k = 0; k < 32; k++) acc += fabsf(W[base + k * 256]);
#pragma unroll
        for (int off = 1; off < 64; off <<= 1) acc += __shfl_xor(acc, off, 64);
        if ((tid & 63) == 0) r4[tid >> 6] = acc;
        __syncthreads();
        if (tid == 0) partials[bid] = r4[0] + r4[1] + r4[2] + r4[3];
    } else {
        int gid = (bid - 256) * 256 + tid;
        const float4* X4 = (const float4*)X;
        float4 a = X4[gid * 2], b = X4[gid * 2 + 1];
        uint4 o;
        o.x = pack2(f2bf(a.x), f2bf(a.y));
        o.y = pack2(f2bf(a.z), f2bf(a.w));
        o.z = pack2(f2bf(b.x), f2bf(b.y));
        o.w = pack2(f2bf(b.z), f2bf(b.w));
        *(uint4*)&Xb[gid * 8] = o;
    }
}

// ---- WT[n][k] build body (shared) ----
__device__ __forceinline__ void weff_body(const float* __restrict__ W, float inv_s,
                                          u16* __restrict__ WT, int bid, int tid,
                                          float* __restrict__ Tt) {
    int combo = bid >> 4, sub = bid & 15;
    int j = combo >> 3, kblk = combo & 7;
    int i = 0;
#pragma unroll
    for (int ii = 0; ii < 8; ii++)
        if (d_OCT_IDX[ii][j] == kblk) i = ii;
    float sign = d_OCT_SIGN[i][j];
    int p0 = (sub >> 2) * 64, q0 = (sub & 3) * 64;
#pragma unroll
    for (int pass = 0; pass < 4; pass++) {
        int p = p0 + pass * 16 + (tid >> 4);
        int q = q0 + (tid & 15) * 4;
        float4 wv = *(const float4*)&W[i * 65536 + p * 256 + q];
        float* Tp = &Tt[(pass * 16 + (tid >> 4)) * 68 + (tid & 15) * 4];
        Tp[0] = sign * rintf(fminf(1.f, fmaxf(-1.f, wv.x * inv_s)));
        Tp[1] = sign * rintf(fminf(1.f, fmaxf(-1.f, wv.y * inv_s)));
        Tp[2] = sign * rintf(fminf(1.f, fmaxf(-1.f, wv.z * inv_s)));
        Tp[3] = sign * rintf(fminf(1.f, fmaxf(-1.f, wv.w * inv_s)));
    }
    __syncthreads();
#pragma unroll
    for (int pass = 0; pass < 2; pass++) {
        int qq = pass * 32 + (tid >> 3);
        int pl = (tid & 7) * 8;
        u16 r[8];
#pragma unroll
        for (int l = 0; l < 8; l++) r[l] = f2bf_trunc(Tt[(pl + l) * 68 + qq]);
        uint4 o;
        o.x = pack2(r[0], r[1]); o.y = pack2(r[2], r[3]);
        o.z = pack2(r[4], r[5]); o.w = pack2(r[6], r[7]);
        *(uint4*)&WT[(size_t)(kblk * 256 + q0 + qq) * 2048 + j * 256 + p0 + pl] = o;
    }
}

__global__ __launch_bounds__(256) void build_weff_kernel(
    const float* __restrict__ W, const float* __restrict__ partials, int wsel,
    u16* __restrict__ WT) {
    __shared__ float Tt[64 * 68];
    __shared__ float s_sh;
    float s = derive_s(partials, wsel, threadIdx.x, &s_sh);
    weff_body(W, 1.0f / s, WT, blockIdx.x, threadIdx.x, Tt);
}

// all 4 weights in one launch: grid 4096, wsel = blockIdx>>10
__global__ __launch_bounds__(256) void build_all_kernel(
    const float* __restrict__ w0, const float* __restrict__ w1,
    const float* __restrict__ w2, const float* __restrict__ w3,
    const float* __restrict__ partials, u16* __restrict__ WTbase) {
    __shared__ float Tt[64 * 68];
    __shared__ float s_sh;
    int wsel = blockIdx.x >> 10;
    const float* W = wsel == 0 ? w0 : wsel == 1 ? w1 : wsel == 2 ? w2 : w3;
    float s = derive_s(partials, wsel, threadIdx.x, &s_sh);
    weff_body(W, 1.0f / s, WTbase + (size_t)wsel * 4194304,
              blockIdx.x & 1023, threadIdx.x, Tt);
}

// ======== R1-frozen GEMM inner loop (folded single-barrier dbuf, BK=64) ========
// T1 chunked XCD swizzle on the 512-block grid (vid = (hid&7)*64 + hid>>3) [R9, kept].
// MODE 1: f32 row-major; MODE 2: bf16 VT[(b*16+h)*128+d][t]
template <int MODE>
__global__ __launch_bounds__(256) void gemm_kernel(
    const u16* __restrict__ A, const u16* __restrict__ Bt,
    const float* __restrict__ partials, int wsel, void* __restrict__ Cout) {
    __shared__ __align__(16) u16 As[2][128 * 64];
    __shared__ __align__(16) u16 Bs[2][128 * 64];
    __shared__ float s_sh;
    const int K = 2048;
    const int NIT = K / 64;
    int tid = threadIdx.x, lane = tid & 63, wid = tid >> 6;
    int quad = lane >> 4, l16 = lane & 15;
    int wm = (wid >> 1) * 64, wn = (wid & 1) * 64;
    int hid = blockIdx.x + 16 * blockIdx.y;
    int vid = (hid & 7) * 64 + (hid >> 3);
    int n0 = (vid & 15) * 128;
    int m0 = (vid >> 4) * 128;
    float s = derive_s(partials, wsel, tid, &s_sh);
    f32x4 acc[4][4];
#pragma unroll
    for (int a = 0; a < 4; a++)
#pragma unroll
        for (int b = 0; b < 4; b++) acc[a][b] = (f32x4){0.f, 0.f, 0.f, 0.f};
    int sr = lane >> 3, sb = lane & 7;
    const u16* Ag = A + (size_t)(m0 + wid * 32 + sr) * K + ((sb ^ sr) * 8);
    const u16* Bg = Bt + (size_t)(n0 + wid * 32 + sr) * K + ((sb ^ sr) * 8);
#pragma unroll
    for (int cc = 0; cc < 4; cc++) {
        async16(Ag + (size_t)cc * 8 * K, &As[0][(wid * 32 + cc * 8) * 64]);
        async16(Bg + (size_t)cc * 8 * K, &Bs[0][(wid * 32 + cc * 8) * 64]);
    }
    for (int g = 0; g < NIT; g++) {
        int c = g & 1;
        __syncthreads();
        if (g + 1 < NIT) {
            int k1 = (g + 1) * 64;
#pragma unroll
            for (int cc = 0; cc < 4; cc++) {
                async16(Ag + k1 + (size_t)cc * 8 * K, &As[1 - c][(wid * 32 + cc * 8) * 64]);
                async16(Bg + k1 + (size_t)cc * 8 * K, &Bs[1 - c][(wid * 32 + cc * 8) * 64]);
            }
        }
#pragma unroll
        for (int kc = 0; kc < 2; kc++) {
            short8 af[4], bfv[4];
#pragma unroll
            for (int mt = 0; mt < 4; mt++)
                af[mt] = *(const short8*)&As[c][(wm + mt * 16 + l16) * 64 + (((kc << 2) | quad) ^ (l16 & 7)) * 8];
#pragma unroll
            for (int nt = 0; nt < 4; nt++)
                bfv[nt] = *(const short8*)&Bs[c][(wn + nt * 16 + l16) * 64 + (((kc << 2) | quad) ^ (l16 & 7)) * 8];
#pragma unroll
            for (int mt = 0; mt < 4; mt++)
#pragma unroll
                for (int nt = 0; nt < 4; nt++)
                    acc[mt][nt] = __builtin_amdgcn_mfma_f32_16x16x32_bf16(af[mt], bfv[nt], acc[mt][nt], 0, 0, 0);
        }
    }
#pragma unroll
    for (int mt = 0; mt < 4; mt++)
#pragma unroll
        for (int nt = 0; nt < 4; nt++) {
            int mg = m0 + wm + mt * 16 + quad * 4;
            int ng = n0 + wn + nt * 16 + l16;
            if (MODE == 1) {
#pragma unroll
                for (int r = 0; r < 4; r++)
                    ((float*)Cout)[(size_t)(mg + r) * 2048 + ng] = acc[mt][nt][r] * s;
            } else {
                ushort4 o4;
                o4.x = f2bf(acc[mt][nt][0] * s);
                o4.y = f2bf(acc[mt][nt][1] * s);
                o4.z = f2bf(acc[mt][nt][2] * s);
                o4.w = f2bf(acc[mt][nt][3] * s);
                *(ushort4*)&((u16*)Cout)[((size_t)((mg >> 11) * 16 + (ng >> 7)) * 128 + (ng & 127)) * 2048 + (mg & 2047)] = o4;
            }
        }
}

// ---- QKV GEMM with fused RoPE epilogue. grid (16,32,NZ):
// wsel = wbase+z. z==0 with qscale -> Q-rope; z==1 (or fallback K-launch w/ qscale=1) -> K-rope;
// z==2 -> V transposed store. z-slab identity + per-slab chunked XCD swizzle [R10].
__global__ __launch_bounds__(256) void gemm_qkv_kernel(
    const u16* __restrict__ A, const u16* __restrict__ WT0,
    const float* __restrict__ partials, int wbase, u16* __restrict__ Cbase,
    const float* __restrict__ fc, const float* __restrict__ fs, float qscale) {
    __shared__ __align__(16) u16 As[2][128 * 64];
    __shared__ __align__(16) u16 Bs[2][128 * 64];
    __shared__ float s_sh;
    const int K = 2048;
    const int NIT = K / 64;
    int z = blockIdx.z;
    int hid = blockIdx.x + 16 * blockIdx.y;
    int vid = (hid & 7) * 64 + (hid >> 3);
    int n0 = (vid & 15) * 128;
    int m0 = (vid >> 4) * 128;
    const u16* Bt = WT0 + (size_t)z * 4194304;    // WT stride: 2048*2048 u16
    u16* Cout = Cbase + (size_t)z * 8388608;      // tensor stride: 4096*2048 u16
    int tid = threadIdx.x, lane = tid & 63, wid = tid >> 6;
    int quad = lane >> 4, l16 = lane & 15;
    int wm = (wid >> 1) * 64, wn = (wid & 1) * 64;
    float s = derive_s(partials, wbase + z, tid, &s_sh);
    f32x4 acc[4][4];
#pragma unroll
    for (int a = 0; a < 4; a++)
#pragma unroll
        for (int b = 0; b < 4; b++) acc[a][b] = (f32x4){0.f, 0.f, 0.f, 0.f};
    int sr = lane >> 3, sb = lane & 7;
    const u16* Ag = A + (size_t)(m0 + wid * 32 + sr) * K + ((sb ^ sr) * 8);
    const u16* Bg = Bt + (size_t)(n0 + wid * 32 + sr) * K + ((sb ^ sr) * 8);
#pragma unroll
    for (int cc = 0; cc < 4; cc++) {
        async16(Ag + (size_t)cc * 8 * K, &As[0][(wid * 32 + cc * 8) * 64]);
        async16(Bg + (size_t)cc * 8 * K, &Bs[0][(wid * 32 + cc * 8) * 64]);
    }
    for (int g = 0; g < NIT; g++) {
        int c = g & 1;
        __syncthreads();
        if (g + 1 < NIT) {
            int k1 = (g + 1) * 64;
#pragma unroll
            for (int cc = 0; cc < 4; cc++) {
                async16(Ag + k1 + (size_t)cc * 8 * K, &As[1 - c][(wid * 32 + cc * 8) * 64]);
                async16(Bg + k1 + (size_t)cc * 8 * K, &Bs[1 - c][(wid * 32 + cc * 8) * 64]);
            }
        }
#pragma unroll
        for (int kc = 0; kc < 2; kc++) {
            short8 af[4], bfv[4];
#pragma unroll
            for (int mt = 0; mt < 4; mt++)
                af[mt] = *(const short8*)&As[c][(wm + mt * 16 + l16) * 64 + (((kc << 2) | quad) ^ (l16 & 7)) * 8];
#pragma unroll
            for (int nt = 0; nt < 4; nt++)
                bfv[nt] = *(const short8*)&Bs[c][(wn + nt * 16 + l16) * 64 + (((kc << 2) | quad) ^ (l16 & 7)) * 8];
#pragma unroll
            for (int mt = 0; mt < 4; mt++)
#pragma unroll
                for (int nt = 0; nt < 4; nt++)
                    acc[mt][nt] = __builtin_amdgcn_mfma_f32_16x16x32_bf16(af[mt], bfv[nt], acc[mt][nt], 0, 0, 0);
        }
    }
    if (z < 2) {
        float rsc = (z == 0) ? qscale : 1.0f;
        float sgn = (l16 & 1) ? 1.f : -1.f;   // even col: xr*c - xi*s ; odd col: xr*s + xi*c
#pragma unroll
        for (int mt = 0; mt < 4; mt++)
#pragma unroll
            for (int nt = 0; nt < 4; nt++) {
                int mg = m0 + wm + mt * 16 + quad * 4;
                int ng = n0 + wn + nt * 16 + l16;
                int m = (ng >> 1) & 63;
#pragma unroll
                for (int r = 0; r < 4; r++) {
                    float v = acc[mt][nt][r] * s;
                    float pv = __shfl_xor(v, 1, 64);   // partner column value
                    int t = (mg + r) & 2047;
                    float cv = fc[t * 64 + m] * rsc;
                    float sv = fs[t * 64 + m] * rsc;
                    Cout[(size_t)(mg + r) * 2048 + ng] = f2bf(v * cv + pv * sv * sgn);
                }
            }
    } else {
#pragma unroll
        for (int mt = 0; mt < 4; mt++)
#pragma unroll
            for (int nt = 0; nt < 4; nt++) {
                int mg = m0 + wm + mt * 16 + quad * 4;
                int ng = n0 + wn + nt * 16 + l16;
                ushort4 o4;
                o4.x = f2bf(acc[mt][nt][0] * s);
                o4.y = f2bf(acc[mt][nt][1] * s);
                o4.z = f2bf(acc[mt][nt][2] * s);
                o4.w = f2bf(acc[mt][nt][3] * s);
                *(ushort4*)&Cout[((size_t)((mg >> 11) * 16 + (ng >> 7)) * 128 + (ng & 127)) * 2048 + (mg & 2047)] = o4;
            }
    }
}

// ---- folded, double-buffered flash (R0 structure) + T13 defer-max (verified R5/R8) ----
__global__ __launch_bounds__(512, 2) void flash_kernel(
    const u16* __restrict__ Q, const u16* __restrict__ Kg,
    const u16* __restrict__ VTg, u16* __restrict__ Y) {
    __shared__ __align__(16) u16 Ks[2][64 * 128];
    __shared__ __align__(16) u16 Vs[2][128 * 64];
    __shared__ __align__(16) u16 Ps[8 * 16 * 64];
    const int NIT = 34;
    int tid = threadIdx.x, lane = tid & 63, wid = tid >> 6;
    int quad = lane >> 4, l16 = lane & 15;
    int bh = blockIdx.x, b = bh >> 4, h = bh & 15;
    int qt = blockIdx.y;
    int nitA = 2 * qt + 2;
    const u16* Qb = Q + (size_t)b * 2048 * 2048 + h * 128;
    const u16* Kb = Kg + (size_t)b * 2048 * 2048 + h * 128;
    const u16* Vb = VTg + (size_t)bh * 128 * 2048;
    int q0 = qt * 128, nit = nitA;
    int ksr = lane >> 4, ksb = lane & 15;
    int vsr = lane >> 3, vsb = lane & 7;
#pragma unroll
    for (int cc = 0; cc < 2; cc++) {
        int ch = wid * 2 + cc;
        int kr = ch * 4 + ksr;
        async16(&Kb[(size_t)kr * 2048 + (ksb ^ (kr & 15)) * 8], &Ks[0][ch * 512]);
        int vd = ch * 8 + vsr;
        async16(&Vb[(size_t)vd * 2048 + (vsb ^ (vd & 7)) * 8], &Vs[0][ch * 512]);
    }
    short8 qf[4];
#pragma unroll
    for (int kt = 0; kt < 4; kt++)
        qf[kt] = *(const short8*)&Qb[(size_t)(q0 + wid * 16 + l16) * 2048 + kt * 32 + quad * 8];
    f32x4 o[8];
#pragma unroll
    for (int nt = 0; nt < 8; nt++) o[nt] = (f32x4){0.f, 0.f, 0.f, 0.f};
    float m_[4] = {-1e30f, -1e30f, -1e30f, -1e30f};
    float l_[4] = {0.f, 0.f, 0.f, 0.f};
    int il = 0;
    for (int g = 0; g < NIT; g++) {
        int c = g & 1;
        __syncthreads();
        if (g + 1 < NIT) {
            int gn = g + 1;
            int s0n = (gn < nitA ? gn : gn - nitA) * 64;
#pragma unroll
            for (int cc = 0; cc < 2; cc++) {
                int ch = wid * 2 + cc;
                int kr = ch * 4 + ksr;
                async16(&Kb[(size_t)(s0n + kr) * 2048 + (ksb ^ (kr & 15)) * 8], &Ks[1 - c][ch * 512]);
                int vd = ch * 8 + vsr;
                async16(&Vb[(size_t)vd * 2048 + s0n + (vsb ^ (vd & 7)) * 8], &Vs[1 - c][ch * 512]);
            }
        }
        int s0 = il * 64;
        f32x4 sc[4];
#pragma unroll
        for (int ct = 0; ct < 4; ct++) {
            f32x4 a = (f32x4){0.f, 0.f, 0.f, 0.f};
#pragma unroll
            for (int kt = 0; kt < 4; kt++) {
                short8 bfv = *(const short8*)&Ks[c][(ct * 16 + l16) * 128 + ((kt * 4 + quad) ^ l16) * 8];
                a = __builtin_amdgcn_mfma_f32_16x16x32_bf16(qf[kt], bfv, a, 0, 0, 0);
            }
            sc[ct] = a;
        }
        if (il >= nit - 2) {
#pragma unroll
            for (int ct = 0; ct < 4; ct++) {
                int colg = s0 + ct * 16 + l16;
#pragma unroll
                for (int r = 0; r < 4; r++) {
                    int rowg = q0 + wid * 16 + quad * 4 + r;
                    if (colg > rowg) sc[ct][r] = -1e30f;
                }
            }
        }
        float mx[4];
#pragma unroll
        for (int r = 0; r < 4; r++) {
            float m2 = fmaxf(fmaxf(sc[0][r], sc[1][r]), fmaxf(sc[2][r], sc[3][r]));
#pragma unroll
            for (int off = 1; off < 16; off <<= 1) m2 = fmaxf(m2, __shfl_xor(m2, off, 64));
            mx[r] = m2;
        }
        bool need = (mx[0] > m_[0] + 8.f) || (mx[1] > m_[1] + 8.f) ||
                    (mx[2] > m_[2] + 8.f) || (mx[3] > m_[3] + 8.f);
        if (__any(need)) {
#pragma unroll
            for (int r = 0; r < 4; r++) {
                float mn = fmaxf(m_[r], mx[r]);
                float al = exp2f(m_[r] - mn);
                m_[r] = mn;
                l_[r] *= al;
#pragma unroll
                for (int nt = 0; nt < 8; nt++) o[nt][r] *= al;
            }
        }
#pragma unroll
        for (int r = 0; r < 4; r++) {
            float rs = 0.f;
#pragma unroll
            for (int ct = 0; ct < 4; ct++) {
                float p = exp2f(sc[ct][r] - m_[r]);
                sc[ct][r] = p;
                rs += p;
            }
#pragma unroll
            for (int off = 1; off < 16; off <<= 1) rs += __shfl_xor(rs, off, 64);
            l_[r] += rs;
        }
        u16* Pw = &Ps[wid * 1024];
#pragma unroll
        for (int ct = 0; ct < 4; ct++)
#pragma unroll
            for (int r = 0; r < 4; r++) {
                int lr = quad * 4 + r;
                int key = ct * 16 + l16;
                Pw[lr * 64 + ((key >> 3) ^ (lr & 7)) * 8 + (key & 7)] = f2bf_trunc(sc[ct][r]);
            }
#pragma unroll
        for (int kt2 = 0; kt2 < 2; kt2++) {
            short8 pa = *(const short8*)&Pw[l16 * 64 + ((kt2 * 4 + quad) ^ (l16 & 7)) * 8];
#pragma unroll
            for (int nt = 0; nt < 8; nt++) {
                short8 vb = *(const short8*)&Vs[c][(nt * 16 + l16) * 64 + ((kt2 * 4 + quad) ^ (l16 & 7)) * 8];
                o[nt] = __builtin_amdgcn_mfma_f32_16x16x32_bf16(pa, vb, o[nt], 0, 0, 0);
            }
        }
        il++;
        if (il == nit && g + 1 < NIT) {
            float iv[4];
#pragma unroll
            for (int r = 0; r < 4; r++) iv[r] = 1.f / l_[r];
#pragma unroll
            for (int nt = 0; nt < 8; nt++)
#pragma unroll
                for (int r = 0; r < 4; r++) {
                    int t_ = q0 + wid * 16 + quad * 4 + r;
                    Y[((size_t)(b * 2048 + t_)) * 2048 + h * 128 + nt * 16 + l16] = f2bf(o[nt][r] * iv[r]);
                }
            q0 = (15 - qt) * 128;
            nit = NIT - nitA;
            il = 0;
#pragma unroll
            for (int kt = 0; kt < 4; kt++)
                qf[kt] = *(const short8*)&Qb[(size_t)(q0 + wid * 16 + l16) * 2048 + kt * 32 + quad * 8];
#pragma unroll
            for (int nt = 0; nt < 8; nt++) o[nt] = (f32x4){0.f, 0.f, 0.f, 0.f};
#pragma unroll
            for (int r = 0; r < 4; r++) { m_[r] = -1e30f; l_[r] = 0.f; }
        }
    }
    float iv[4];
#pragma unroll
    for (int r = 0; r < 4; r++) iv[r] = 1.f / l_[r];
#pragma unroll
    for (int nt = 0; nt < 8; nt++)
#pragma unroll
        for (int r = 0; r < 4; r++) {
            int t_ = q0 + wid * 16 + quad * 4 + r;
            Y[((size_t)(b * 2048 + t_)) * 2048 + h * 128 + nt * 16 + l16] = f2bf(o[nt][r] * iv[r]);
        }
}

extern "C" void kernel_launch(void* const* d_in, const int* in_sizes, int n_in,
                              void* d_out, int out_size, void* d_ws, size_t ws_size,
                              hipStream_t stream) {
    const float* x  = (const float*)d_in[0];
    const float* wq = (const float*)d_in[1];
    const float* wk = (const float*)d_in[2];
    const float* wv = (const float*)d_in[3];
    const float* wo = (const float*)d_in[4];
    const float* fc = (const float*)d_in[5];
    const float* fs = (const float*)d_in[6];
    float* out = (float*)d_out;

    const float QSCALE = 0.08838834764831845f * 1.4426950408889634f;  // 1/sqrt(128)*log2(e)
    char* ws = (char*)d_ws;
    float* partials = (float*)(ws + 1024);

    // Element counts: WT = 2048*2048 = 4,194,304 u16 (8 MB each);
    //                 xb/Q/K/VT = 4096*2048 = 8,388,608 u16 (16 MB each).
    const size_t FUSED_NEED = 8192 + 4ull * 8388608 /*4 WT*/ + 16777216 /*xb*/
                            + 3ull * 16777216 /*QKV*/;   // ~96.01 MB
    if (ws_size >= FUSED_NEED) {
        // 5 launches
        u16* WT  = (u16*)(ws + 8192);          // 4 x 4,194,304 u16
        u16* xb  = WT + 4ull * 4194304;        // 8,388,608 u16
        u16* Qb  = xb + 8388608;
        u16* Kb  = Qb + 8388608;
        u16* VTb = Kb + 8388608;

        pre_kernel<<<4352, 256, 0, stream>>>(wq, wk, wv, wo, x, partials, xb);
        build_all_kernel<<<4096, 256, 0, stream>>>(wq, wk, wv, wo, partials, WT);
        gemm_qkv_kernel<<<dim3(16, 32, 3), 256, 0, stream>>>(xb, WT, partials, 0, Qb, fc, fs, QSCALE);
        flash_kernel<<<dim3(32, 8), 512, 0, stream>>>(Qb, Kb, VTb, Qb /* Y aliases Q */);
        gemm_kernel<1><<<dim3(16, 32), 256, 0, stream>>>(Qb, WT + 3ull * 4194304,
                                                         partials, 3, (void*)out);
    } else {
        // fallback: proven 72 MB layout, 10 launches
        u16* WT  = (u16*)(ws + 8192);
        u16* xb  = (u16*)(ws + 8192 + 8388608);
        u16* Qb  = xb + 8388608;
        u16* Kb  = Qb + 8388608;
        u16* VTb = Kb + 8388608;

        pre_kernel<<<4352, 256, 0, stream>>>(wq, wk, wv, wo, x, partials, xb);

        build_weff_kernel<<<1024, 256, 0, stream>>>(wq, partials, 0, WT);
        gemm_qkv_kernel<<<dim3(16, 32, 1), 256, 0, stream>>>(xb, WT, partials, 0, Qb, fc, fs, QSCALE);

        build_weff_kernel<<<1024, 256, 0, stream>>>(wk, partials, 1, WT);
        gemm_qkv_kernel<<<dim3(16, 32, 1), 256, 0, stream>>>(xb, WT, partials, 1, Kb, fc, fs, 1.0f);

        build_weff_kernel<<<1024, 256, 0, stream>>>(wv, partials, 2, WT);
        gemm_kernel<2><<<dim3(16, 32), 256, 0, stream>>>(xb, WT, partials, 2, VTb);

        flash_kernel<<<dim3(32, 8), 512, 0, stream>>>(Qb, Kb, VTb, Qb);

        build_weff_kernel<<<1024, 256, 0, stream>>>(wo, partials, 3, WT);
        gemm_kernel<1><<<dim3(16, 32), 256, 0, stream>>>(Qb, WT, partials, 3, (void*)out);
    }
}

// Round 12
// 352.215 us; speedup vs baseline: 1.0134x; 1.0134x over previous
//
#include <hip/hip_runtime.h>

// B=2, T=2048, C=2048, H=16, HD=128, P=256
// s=mean|W| -> WT ternary bf16 [n][k] -> async-LDS bf16 GEMMs -> flash -> out GEMM
// R1:  GEMM folded single-barrier dbuf BK=64, 128x128, 256 thr == FROZEN (2-phase ceiling)
// R8:  RoPE fused into Q/K GEMM epilogue; build_all + gemm_qkv(z=3)          (363.7us)
// R9:  out-GEMM chunked T1 XCD swizzle                                       (354.4us)
// R10: gemm_qkv z-slab identity + per-slab chunked swizzle -> 733 TF ceiling (355.1us)
// R11: (split result) pre_kernel fusion GOOD (-18us non-qkv) but derive_s preamble
//      in GEMMs BAD (qkv 141->161: preamble perturbs frozen body, rule #19)
// R12: recombine -- pre_kernel kept, reduce2 restored, ALL GEMM/build bodies reverted
//      to byte-identical R10 form (s_vals scalar read after loop). 6 launches.

typedef __attribute__((ext_vector_type(8))) short short8;
typedef __attribute__((ext_vector_type(4))) float f32x4;
typedef unsigned short u16;
typedef unsigned int u32;

__device__ __forceinline__ float bf2f(u16 u) {
    u32 x = ((u32)u) << 16;
    return __builtin_bit_cast(float, x);
}
__device__ __forceinline__ u16 f2bf(float f) {
    u32 x = __builtin_bit_cast(u32, f);
    x += 0x7fffu + ((x >> 16) & 1u);   // RNE
    return (u16)(x >> 16);
}
__device__ __forceinline__ u16 f2bf_trunc(float f) {
    return (u16)(__builtin_bit_cast(u32, f) >> 16);
}
__device__ __forceinline__ u32 pack2(u16 a, u16 b) { return (u32)a | ((u32)b << 16); }

__device__ __forceinline__ void async16(const void* g, void* l) {
    __builtin_amdgcn_global_load_lds((const __attribute__((address_space(1))) u32*)g,
                                     (__attribute__((address_space(3))) u32*)l, 16, 0, 0);
}

__device__ const int d_OCT_IDX[8][8] = {
    {0,1,2,3,4,5,6,7},{1,0,3,2,5,4,7,6},{2,3,0,1,6,7,4,5},{3,2,1,0,7,6,5,4},
    {4,5,6,7,0,1,2,3},{5,4,7,6,1,0,3,2},{6,7,4,5,2,3,0,1},{7,6,5,4,3,2,1,0}};
__device__ const float d_OCT_SIGN[8][8] = {
    { 1, 1, 1, 1, 1, 1, 1, 1},{ 1,-1, 1,-1, 1,-1,-1, 1},{ 1,-1,-1, 1, 1, 1,-1,-1},
    { 1, 1,-1,-1, 1,-1, 1,-1},{ 1,-1,-1,-1,-1, 1, 1, 1},{ 1, 1,-1, 1,-1,-1,-1, 1},
    { 1, 1, 1,-1,-1, 1,-1,-1},{ 1,-1, 1, 1,-1,-1, 1,-1}};

// ---- pre: blocks [0,256) = |W| partial sums; blocks [256,4352) = x f32->bf16 cast ----
__global__ __launch_bounds__(256) void pre_kernel(
    const float* __restrict__ w0, const float* __restrict__ w1,
    const float* __restrict__ w2, const float* __restrict__ w3,
    const float* __restrict__ X, float* __restrict__ partials, u16* __restrict__ Xb) {
    __shared__ float r4[4];
    int bid = blockIdx.x, tid = threadIdx.x;
    if (bid < 256) {
        int wsel = bid >> 6, part = bid & 63;
        const float* W = wsel == 0 ? w0 : wsel == 1 ? w1 : wsel == 2 ? w2 : w3;
        int base = part * 8192 + tid;
        float acc = 0.f;
#pragma unroll
        for (int k = 0; k < 32; k++) acc += fabsf(W[base + k * 256]);
#pragma unroll
        for (int off = 1; off < 64; off <<= 1) acc += __shfl_xor(acc, off, 64);
        if ((tid & 63) == 0) r4[tid >> 6] = acc;
        __syncthreads();
        if (tid == 0) partials[bid] = r4[0] + r4[1] + r4[2] + r4[3];
    } else {
        int gid = (bid - 256) * 256 + tid;
        const float4* X4 = (const float4*)X;
        float4 a = X4[gid * 2], b = X4[gid * 2 + 1];
        uint4 o;
        o.x = pack2(f2bf(a.x), f2bf(a.y));
        o.y = pack2(f2bf(a.z), f2bf(a.w));
        o.z = pack2(f2bf(b.x), f2bf(b.y));
        o.w = pack2(f2bf(b.z), f2bf(b.w));
        *(uint4*)&Xb[gid * 8] = o;
    }
}

__global__ __launch_bounds__(256) void reduce2_kernel(const float* __restrict__ partials,
                                                      float* __restrict__ s_vals) {
    int w = threadIdx.x >> 6, lane = threadIdx.x & 63;
    float v = partials[w * 64 + lane];
#pragma unroll
    for (int off = 1; off < 64; off <<= 1) v += __shfl_xor(v, off, 64);
    if (lane == 0) s_vals[w] = v / 524288.0f + 1e-8f;
}

// ---- WT[n][k] build body (shared) ----
__device__ __forceinline__ void weff_body(const float* __restrict__ W, float inv_s,
                                          u16* __restrict__ WT, int bid, int tid,
                                          float* __restrict__ Tt) {
    int combo = bid >> 4, sub = bid & 15;
    int j = combo >> 3, kblk = combo & 7;
    int i = 0;
#pragma unroll
    for (int ii = 0; ii < 8; ii++)
        if (d_OCT_IDX[ii][j] == kblk) i = ii;
    float sign = d_OCT_SIGN[i][j];
    int p0 = (sub >> 2) * 64, q0 = (sub & 3) * 64;
#pragma unroll
    for (int pass = 0; pass < 4; pass++) {
        int p = p0 + pass * 16 + (tid >> 4);
        int q = q0 + (tid & 15) * 4;
        float4 wv = *(const float4*)&W[i * 65536 + p * 256 + q];
        float* Tp = &Tt[(pass * 16 + (tid >> 4)) * 68 + (tid & 15) * 4];
        Tp[0] = sign * rintf(fminf(1.f, fmaxf(-1.f, wv.x * inv_s)));
        Tp[1] = sign * rintf(fminf(1.f, fmaxf(-1.f, wv.y * inv_s)));
        Tp[2] = sign * rintf(fminf(1.f, fmaxf(-1.f, wv.z * inv_s)));
        Tp[3] = sign * rintf(fminf(1.f, fmaxf(-1.f, wv.w * inv_s)));
    }
    __syncthreads();
#pragma unroll
    for (int pass = 0; pass < 2; pass++) {
        int qq = pass * 32 + (tid >> 3);
        int pl = (tid & 7) * 8;
        u16 r[8];
#pragma unroll
        for (int l = 0; l < 8; l++) r[l] = f2bf_trunc(Tt[(pl + l) * 68 + qq]);
        uint4 o;
        o.x = pack2(r[0], r[1]); o.y = pack2(r[2], r[3]);
        o.z = pack2(r[4], r[5]); o.w = pack2(r[6], r[7]);
        *(uint4*)&WT[(size_t)(kblk * 256 + q0 + qq) * 2048 + j * 256 + p0 + pl] = o;
    }
}

__global__ __launch_bounds__(256) void build_weff_kernel(
    const float* __restrict__ W, const float* __restrict__ sptr, u16* __restrict__ WT) {
    __shared__ float Tt[64 * 68];
    weff_body(W, 1.0f / (*sptr), WT, blockIdx.x, threadIdx.x, Tt);
}

// all 4 weights in one launch: grid 4096, wsel = blockIdx>>10
__global__ __launch_bounds__(256) void build_all_kernel(
    const float* __restrict__ w0, const float* __restrict__ w1,
    const float* __restrict__ w2, const float* __restrict__ w3,
    const float* __restrict__ s_vals, u16* __restrict__ WTbase) {
    __shared__ float Tt[64 * 68];
    int wsel = blockIdx.x >> 10;
    const float* W = wsel == 0 ? w0 : wsel == 1 ? w1 : wsel == 2 ? w2 : w3;
    weff_body(W, 1.0f / s_vals[wsel], WTbase + (size_t)wsel * 4194304,
              blockIdx.x & 1023, threadIdx.x, Tt);
}

// ======== R1-frozen GEMM inner loop (folded single-barrier dbuf, BK=64) ========
// T1 chunked XCD swizzle on the 512-block grid (vid = (hid&7)*64 + hid>>3) [R9].
// MODE 1: f32 row-major; MODE 2: bf16 VT[(b*16+h)*128+d][t]
template <int MODE>
__global__ __launch_bounds__(256) void gemm_kernel(
    const u16* __restrict__ A, const u16* __restrict__ Bt,
    const float* __restrict__ sptr, void* __restrict__ Cout) {
    __shared__ __align__(16) u16 As[2][128 * 64];
    __shared__ __align__(16) u16 Bs[2][128 * 64];
    const int K = 2048;
    const int NIT = K / 64;
    int tid = threadIdx.x, lane = tid & 63, wid = tid >> 6;
    int quad = lane >> 4, l16 = lane & 15;
    int wm = (wid >> 1) * 64, wn = (wid & 1) * 64;
    int hid = blockIdx.x + 16 * blockIdx.y;
    int vid = (hid & 7) * 64 + (hid >> 3);
    int n0 = (vid & 15) * 128;
    int m0 = (vid >> 4) * 128;
    f32x4 acc[4][4];
#pragma unroll
    for (int a = 0; a < 4; a++)
#pragma unroll
        for (int b = 0; b < 4; b++) acc[a][b] = (f32x4){0.f, 0.f, 0.f, 0.f};
    int sr = lane >> 3, sb = lane & 7;
    const u16* Ag = A + (size_t)(m0 + wid * 32 + sr) * K + ((sb ^ sr) * 8);
    const u16* Bg = Bt + (size_t)(n0 + wid * 32 + sr) * K + ((sb ^ sr) * 8);
#pragma unroll
    for (int cc = 0; cc < 4; cc++) {
        async16(Ag + (size_t)cc * 8 * K, &As[0][(wid * 32 + cc * 8) * 64]);
        async16(Bg + (size_t)cc * 8 * K, &Bs[0][(wid * 32 + cc * 8) * 64]);
    }
    for (int g = 0; g < NIT; g++) {
        int c = g & 1;
        __syncthreads();
        if (g + 1 < NIT) {
            int k1 = (g + 1) * 64;
#pragma unroll
            for (int cc = 0; cc < 4; cc++) {
                async16(Ag + k1 + (size_t)cc * 8 * K, &As[1 - c][(wid * 32 + cc * 8) * 64]);
                async16(Bg + k1 + (size_t)cc * 8 * K, &Bs[1 - c][(wid * 32 + cc * 8) * 64]);
            }
        }
#pragma unroll
        for (int kc = 0; kc < 2; kc++) {
            short8 af[4], bfv[4];
#pragma unroll
            for (int mt = 0; mt < 4; mt++)
                af[mt] = *(const short8*)&As[c][(wm + mt * 16 + l16) * 64 + (((kc << 2) | quad) ^ (l16 & 7)) * 8];
#pragma unroll
            for (int nt = 0; nt < 4; nt++)
                bfv[nt] = *(const short8*)&Bs[c][(wn + nt * 16 + l16) * 64 + (((kc << 2) | quad) ^ (l16 & 7)) * 8];
#pragma unroll
            for (int mt = 0; mt < 4; mt++)
#pragma unroll
                for (int nt = 0; nt < 4; nt++)
                    acc[mt][nt] = __builtin_amdgcn_mfma_f32_16x16x32_bf16(af[mt], bfv[nt], acc[mt][nt], 0, 0, 0);
        }
    }
    float s = *sptr;
#pragma unroll
    for (int mt = 0; mt < 4; mt++)
#pragma unroll
        for (int nt = 0; nt < 4; nt++) {
            int mg = m0 + wm + mt * 16 + quad * 4;
            int ng = n0 + wn + nt * 16 + l16;
            if (MODE == 1) {
#pragma unroll
                for (int r = 0; r < 4; r++)
                    ((float*)Cout)[(size_t)(mg + r) * 2048 + ng] = acc[mt][nt][r] * s;
            } else {
                ushort4 o4;
                o4.x = f2bf(acc[mt][nt][0] * s);
                o4.y = f2bf(acc[mt][nt][1] * s);
                o4.z = f2bf(acc[mt][nt][2] * s);
                o4.w = f2bf(acc[mt][nt][3] * s);
                *(ushort4*)&((u16*)Cout)[((size_t)((mg >> 11) * 16 + (ng >> 7)) * 128 + (ng & 127)) * 2048 + (mg & 2047)] = o4;
            }
        }
}

// ---- QKV GEMM with fused RoPE epilogue. grid (16,32,NZ):
// z=0: rope scale=qscale (Q); z=1: rope scale=1 (K); z=2: V transposed store.
// z-slab identity (one WT per slab, B-locality) + per-slab chunked XCD swizzle [R10].
__global__ __launch_bounds__(256) void gemm_qkv_kernel(
    const u16* __restrict__ A, const u16* __restrict__ WT0,
    const float* __restrict__ s_vals, u16* __restrict__ Cbase,
    const float* __restrict__ fc, const float* __restrict__ fs, float qscale) {
    __shared__ __align__(16) u16 As[2][128 * 64];
    __shared__ __align__(16) u16 Bs[2][128 * 64];
    const int K = 2048;
    const int NIT = K / 64;
    int z = blockIdx.z;
    int hid = blockIdx.x + 16 * blockIdx.y;
    int vid = (hid & 7) * 64 + (hid >> 3);
    int n0 = (vid & 15) * 128;
    int m0 = (vid >> 4) * 128;
    const u16* Bt = WT0 + (size_t)z * 4194304;    // WT stride: 2048*2048 u16
    u16* Cout = Cbase + (size_t)z * 8388608;      // tensor stride: 4096*2048 u16
    int tid = threadIdx.x, lane = tid & 63, wid = tid >> 6;
    int quad = lane >> 4, l16 = lane & 15;
    int wm = (wid >> 1) * 64, wn = (wid & 1) * 64;
    f32x4 acc[4][4];
#pragma unroll
    for (int a = 0; a < 4; a++)
#pragma unroll
        for (int b = 0; b < 4; b++) acc[a][b] = (f32x4){0.f, 0.f, 0.f, 0.f};
    int sr = lane >> 3, sb = lane & 7;
    const u16* Ag = A + (size_t)(m0 + wid * 32 + sr) * K + ((sb ^ sr) * 8);
    const u16* Bg = Bt + (size_t)(n0 + wid * 32 + sr) * K + ((sb ^ sr) * 8);
#pragma unroll
    for (int cc = 0; cc < 4; cc++) {
        async16(Ag + (size_t)cc * 8 * K, &As[0][(wid * 32 + cc * 8) * 64]);
        async16(Bg + (size_t)cc * 8 * K, &Bs[0][(wid * 32 + cc * 8) * 64]);
    }
    for (int g = 0; g < NIT; g++) {
        int c = g & 1;
        __syncthreads();
        if (g + 1 < NIT) {
            int k1 = (g + 1) * 64;
#pragma unroll
            for (int cc = 0; cc < 4; cc++) {
                async16(Ag + k1 + (size_t)cc * 8 * K, &As[1 - c][(wid * 32 + cc * 8) * 64]);
                async16(Bg + k1 + (size_t)cc * 8 * K, &Bs[1 - c][(wid * 32 + cc * 8) * 64]);
            }
        }
#pragma unroll
        for (int kc = 0; kc < 2; kc++) {
            short8 af[4], bfv[4];
#pragma unroll
            for (int mt = 0; mt < 4; mt++)
                af[mt] = *(const short8*)&As[c][(wm + mt * 16 + l16) * 64 + (((kc << 2) | quad) ^ (l16 & 7)) * 8];
#pragma unroll
            for (int nt = 0; nt < 4; nt++)
                bfv[nt] = *(const short8*)&Bs[c][(wn + nt * 16 + l16) * 64 + (((kc << 2) | quad) ^ (l16 & 7)) * 8];
#pragma unroll
            for (int mt = 0; mt < 4; mt++)
#pragma unroll
                for (int nt = 0; nt < 4; nt++)
                    acc[mt][nt] = __builtin_amdgcn_mfma_f32_16x16x32_bf16(af[mt], bfv[nt], acc[mt][nt], 0, 0, 0);
        }
    }
    float s = s_vals[z];
    if (z < 2) {
        float rsc = (z == 0) ? qscale : 1.0f;
        float sgn = (l16 & 1) ? 1.f : -1.f;   // even col: xr*c - xi*s ; odd col: xr*s + xi*c
#pragma unroll
        for (int mt = 0; mt < 4; mt++)
#pragma unroll
            for (int nt = 0; nt < 4; nt++) {
                int mg = m0 + wm + mt * 16 + quad * 4;
                int ng = n0 + wn + nt * 16 + l16;
                int m = (ng >> 1) & 63;
#pragma unroll
                for (int r = 0; r < 4; r++) {
                    float v = acc[mt][nt][r] * s;
                    float pv = __shfl_xor(v, 1, 64);   // partner column value
                    int t = (mg + r) & 2047;
                    float cv = fc[t * 64 + m] * rsc;
                    float sv = fs[t * 64 + m] * rsc;
                    Cout[(size_t)(mg + r) * 2048 + ng] = f2bf(v * cv + pv * sv * sgn);
                }
            }
    } else {
#pragma unroll
        for (int mt = 0; mt < 4; mt++)
#pragma unroll
            for (int nt = 0; nt < 4; nt++) {
                int mg = m0 + wm + mt * 16 + quad * 4;
                int ng = n0 + wn + nt * 16 + l16;
                ushort4 o4;
                o4.x = f2bf(acc[mt][nt][0] * s);
                o4.y = f2bf(acc[mt][nt][1] * s);
                o4.z = f2bf(acc[mt][nt][2] * s);
                o4.w = f2bf(acc[mt][nt][3] * s);
                *(ushort4*)&Cout[((size_t)((mg >> 11) * 16 + (ng >> 7)) * 128 + (ng & 127)) * 2048 + (mg & 2047)] = o4;
            }
    }
}

// ---- folded, double-buffered flash (R0 structure) + T13 defer-max (verified R5/R8) ----
__global__ __launch_bounds__(512, 2) void flash_kernel(
    const u16* __restrict__ Q, const u16* __restrict__ Kg,
    const u16* __restrict__ VTg, u16* __restrict__ Y) {
    __shared__ __align__(16) u16 Ks[2][64 * 128];
    __shared__ __align__(16) u16 Vs[2][128 * 64];
    __shared__ __align__(16) u16 Ps[8 * 16 * 64];
    const int NIT = 34;
    int tid = threadIdx.x, lane = tid & 63, wid = tid >> 6;
    int quad = lane >> 4, l16 = lane & 15;
    int bh = blockIdx.x, b = bh >> 4, h = bh & 15;
    int qt = blockIdx.y;
    int nitA = 2 * qt + 2;
    const u16* Qb = Q + (size_t)b * 2048 * 2048 + h * 128;
    const u16* Kb = Kg + (size_t)b * 2048 * 2048 + h * 128;
    const u16* Vb = VTg + (size_t)bh * 128 * 2048;
    int q0 = qt * 128, nit = nitA;
    int ksr = lane >> 4, ksb = lane & 15;
    int vsr = lane >> 3, vsb = lane & 7;
#pragma unroll
    for (int cc = 0; cc < 2; cc++) {
        int ch = wid * 2 + cc;
        int kr = ch * 4 + ksr;
        async16(&Kb[(size_t)kr * 2048 + (ksb ^ (kr & 15)) * 8], &Ks[0][ch * 512]);
        int vd = ch * 8 + vsr;
        async16(&Vb[(size_t)vd * 2048 + (vsb ^ (vd & 7)) * 8], &Vs[0][ch * 512]);
    }
    short8 qf[4];
#pragma unroll
    for (int kt = 0; kt < 4; kt++)
        qf[kt] = *(const short8*)&Qb[(size_t)(q0 + wid * 16 + l16) * 2048 + kt * 32 + quad * 8];
    f32x4 o[8];
#pragma unroll
    for (int nt = 0; nt < 8; nt++) o[nt] = (f32x4){0.f, 0.f, 0.f, 0.f};
    float m_[4] = {-1e30f, -1e30f, -1e30f, -1e30f};
    float l_[4] = {0.f, 0.f, 0.f, 0.f};
    int il = 0;
    for (int g = 0; g < NIT; g++) {
        int c = g & 1;
        __syncthreads();
        if (g + 1 < NIT) {
            int gn = g + 1;
            int s0n = (gn < nitA ? gn : gn - nitA) * 64;
#pragma unroll
            for (int cc = 0; cc < 2; cc++) {
                int ch = wid * 2 + cc;
                int kr = ch * 4 + ksr;
                async16(&Kb[(size_t)(s0n + kr) * 2048 + (ksb ^ (kr & 15)) * 8], &Ks[1 - c][ch * 512]);
                int vd = ch * 8 + vsr;
                async16(&Vb[(size_t)vd * 2048 + s0n + (vsb ^ (vd & 7)) * 8], &Vs[1 - c][ch * 512]);
            }
        }
        int s0 = il * 64;
        f32x4 sc[4];
#pragma unroll
        for (int ct = 0; ct < 4; ct++) {
            f32x4 a = (f32x4){0.f, 0.f, 0.f, 0.f};
#pragma unroll
            for (int kt = 0; kt < 4; kt++) {
                short8 bfv = *(const short8*)&Ks[c][(ct * 16 + l16) * 128 + ((kt * 4 + quad) ^ l16) * 8];
                a = __builtin_amdgcn_mfma_f32_16x16x32_bf16(qf[kt], bfv, a, 0, 0, 0);
            }
            sc[ct] = a;
        }
        if (il >= nit - 2) {
#pragma unroll
            for (int ct = 0; ct < 4; ct++) {
                int colg = s0 + ct * 16 + l16;
#pragma unroll
                for (int r = 0; r < 4; r++) {
                    int rowg = q0 + wid * 16 + quad * 4 + r;
                    if (colg > rowg) sc[ct][r] = -1e30f;
                }
            }
        }
        float mx[4];
#pragma unroll
        for (int r = 0; r < 4; r++) {
            float m2 = fmaxf(fmaxf(sc[0][r], sc[1][r]), fmaxf(sc[2][r], sc[3][r]));
#pragma unroll
            for (int off = 1; off < 16; off <<= 1) m2 = fmaxf(m2, __shfl_xor(m2, off, 64));
            mx[r] = m2;
        }
        bool need = (mx[0] > m_[0] + 8.f) || (mx[1] > m_[1] + 8.f) ||
                    (mx[2] > m_[2] + 8.f) || (mx[3] > m_[3] + 8.f);
        if (__any(need)) {
#pragma unroll
            for (int r = 0; r < 4; r++) {
                float mn = fmaxf(m_[r], mx[r]);
                float al = exp2f(m_[r] - mn);
                m_[r] = mn;
                l_[r] *= al;
#pragma unroll
                for (int nt = 0; nt < 8; nt++) o[nt][r] *= al;
            }
        }
#pragma unroll
        for (int r = 0; r < 4; r++) {
            float rs = 0.f;
#pragma unroll
            for (int ct = 0; ct < 4; ct++) {
                float p = exp2f(sc[ct][r] - m_[r]);
                sc[ct][r] = p;
                rs += p;
            }
#pragma unroll
            for (int off = 1; off < 16; off <<= 1) rs += __shfl_xor(rs, off, 64);
            l_[r] += rs;
        }
        u16* Pw = &Ps[wid * 1024];
#pragma unroll
        for (int ct = 0; ct < 4; ct++)
#pragma unroll
            for (int r = 0; r < 4; r++) {
                int lr = quad * 4 + r;
                int key = ct * 16 + l16;
                Pw[lr * 64 + ((key >> 3) ^ (lr & 7)) * 8 + (key & 7)] = f2bf_trunc(sc[ct][r]);
            }
#pragma unroll
        for (int kt2 = 0; kt2 < 2; kt2++) {
            short8 pa = *(const short8*)&Pw[l16 * 64 + ((kt2 * 4 + quad) ^ (l16 & 7)) * 8];
#pragma unroll
            for (int nt = 0; nt < 8; nt++) {
                short8 vb = *(const short8*)&Vs[c][(nt * 16 + l16) * 64 + ((kt2 * 4 + quad) ^ (l16 & 7)) * 8];
                o[nt] = __builtin_amdgcn_mfma_f32_16x16x32_bf16(pa, vb, o[nt], 0, 0, 0);
            }
        }
        il++;
        if (il == nit && g + 1 < NIT) {
            float iv[4];
#pragma unroll
            for (int r = 0; r < 4; r++) iv[r] = 1.f / l_[r];
#pragma unroll
            for (int nt = 0; nt < 8; nt++)
#pragma unroll
                for (int r = 0; r < 4; r++) {
                    int t_ = q0 + wid * 16 + quad * 4 + r;
                    Y[((size_t)(b * 2048 + t_)) * 2048 + h * 128 + nt * 16 + l16] = f2bf(o[nt][r] * iv[r]);
                }
            q0 = (15 - qt) * 128;
            nit = NIT - nitA;
            il = 0;
#pragma unroll
            for (int kt = 0; kt < 4; kt++)
                qf[kt] = *(const short8*)&Qb[(size_t)(q0 + wid * 16 + l16) * 2048 + kt * 32 + quad * 8];
#pragma unroll
            for (int nt = 0; nt < 8; nt++) o[nt] = (f32x4){0.f, 0.f, 0.f, 0.f};
#pragma unroll
            for (int r = 0; r < 4; r++) { m_[r] = -1e30f; l_[r] = 0.f; }
        }
    }
    float iv[4];
#pragma unroll
    for (int r = 0; r < 4; r++) iv[r] = 1.f / l_[r];
#pragma unroll
    for (int nt = 0; nt < 8; nt++)
#pragma unroll
        for (int r = 0; r < 4; r++) {
            int t_ = q0 + wid * 16 + quad * 4 + r;
            Y[((size_t)(b * 2048 + t_)) * 2048 + h * 128 + nt * 16 + l16] = f2bf(o[nt][r] * iv[r]);
        }
}

extern "C" void kernel_launch(void* const* d_in, const int* in_sizes, int n_in,
                              void* d_out, int out_size, void* d_ws, size_t ws_size,
                              hipStream_t stream) {
    const float* x  = (const float*)d_in[0];
    const float* wq = (const float*)d_in[1];
    const float* wk = (const float*)d_in[2];
    const float* wv = (const float*)d_in[3];
    const float* wo = (const float*)d_in[4];
    const float* fc = (const float*)d_in[5];
    const float* fs = (const float*)d_in[6];
    float* out = (float*)d_out;

    const float QSCALE = 0.08838834764831845f * 1.4426950408889634f;  // 1/sqrt(128)*log2(e)
    char* ws = (char*)d_ws;
    float* s_vals   = (float*)ws;
    float* partials = (float*)(ws + 1024);

    // Element counts: WT = 2048*2048 = 4,194,304 u16 (8 MB each);
    //                 xb/Q/K/VT = 4096*2048 = 8,388,608 u16 (16 MB each).
    const size_t FUSED_NEED = 8192 + 4ull * 8388608 /*4 WT*/ + 16777216 /*xb*/
                            + 3ull * 16777216 /*QKV*/;   // ~96.01 MB
    if (ws_size >= FUSED_NEED) {
        // 6 launches
        u16* WT  = (u16*)(ws + 8192);          // 4 x 4,194,304 u16
        u16* xb  = WT + 4ull * 4194304;        // 8,388,608 u16
        u16* Qb  = xb + 8388608;
        u16* Kb  = Qb + 8388608;
        u16* VTb = Kb + 8388608;

        pre_kernel<<<4352, 256, 0, stream>>>(wq, wk, wv, wo, x, partials, xb);
        reduce2_kernel<<<1, 256, 0, stream>>>(partials, s_vals);
        build_all_kernel<<<4096, 256, 0, stream>>>(wq, wk, wv, wo, s_vals, WT);
        gemm_qkv_kernel<<<dim3(16, 32, 3), 256, 0, stream>>>(xb, WT, s_vals, Qb, fc, fs, QSCALE);
        flash_kernel<<<dim3(32, 8), 512, 0, stream>>>(Qb, Kb, VTb, Qb /* Y aliases Q */);
        gemm_kernel<1><<<dim3(16, 32), 256, 0, stream>>>(Qb, WT + 3ull * 4194304,
                                                         s_vals + 3, (void*)out);
    } else {
        // fallback: proven 72 MB layout, 11 launches
        u16* WT  = (u16*)(ws + 8192);
        u16* xb  = (u16*)(ws + 8192 + 8388608);
        u16* Qb  = xb + 8388608;
        u16* Kb  = Qb + 8388608;
        u16* VTb = Kb + 8388608;

        pre_kernel<<<4352, 256, 0, stream>>>(wq, wk, wv, wo, x, partials, xb);
        reduce2_kernel<<<1, 256, 0, stream>>>(partials, s_vals);

        build_weff_kernel<<<1024, 256, 0, stream>>>(wq, s_vals + 0, WT);
        gemm_qkv_kernel<<<dim3(16, 32, 1), 256, 0, stream>>>(xb, WT, s_vals + 0, Qb, fc, fs, QSCALE);

        build_weff_kernel<<<1024, 256, 0, stream>>>(wk, s_vals + 1, WT);
        gemm_qkv_kernel<<<dim3(16, 32, 1), 256, 0, stream>>>(xb, WT, s_vals + 1, Kb, fc, fs, 1.0f);

        build_weff_kernel<<<1024, 256, 0, stream>>>(wv, s_vals + 2, WT);
        gemm_kernel<2><<<dim3(16, 32), 256, 0, stream>>>(xb, WT, s_vals + 2, VTb);

        flash_kernel<<<dim3(32, 8), 512, 0, stream>>>(Qb, Kb, VTb, Qb);

        build_weff_kernel<<<1024, 256, 0, stream>>>(wo, s_vals + 3, WT);
        gemm_kernel<1><<<dim3(16, 32), 256, 0, stream>>>(Qb, WT, s_vals + 3, (void*)out);
    }
}